// Round 1
// baseline (623.445 us; speedup 1.0000x reference)
//
#include <hip/hip_runtime.h>
#include <math.h>

#define HH    768   // hidden dim
#define QL    20    // query tokens
#define SS    512   // seq len
#define DD    492   // doc tokens (512-20)
#define NBATCH 16
#define NLAYER 13   // unique layers (all_layers[0]==all_layers[1])
#define NBINS 11

// One block per unique (layer, batch). 512 threads; thread t owns doc row t.
__global__ __launch_bounds__(512)
void sim_hist_kernel(const float* __restrict__ hs, float* __restrict__ counts) {
    const int l = blockIdx.x;   // 0..12
    const int b = blockIdx.y;   // 0..15
    const float* __restrict__ base = hs + (size_t)(l * NBATCH + b) * SS * HH;

    __shared__ float s_qn[QL];
    __shared__ float s_part[QL * 16];
    __shared__ int   s_hist[NBINS];

    const int t = threadIdx.x;
    if (t < NBINS) s_hist[t] = 0;

    // ---- cooperative q-row norms: 20 rows x 768, 16 partials per row ----
    if (t < QL * 16) {
        const int qi = t >> 4;
        const int p  = t & 15;
        const float* qp = base + qi * HH + p * 48;
        float s = 0.f;
        #pragma unroll
        for (int j = 0; j < 48; j += 4) {
            float4 v = *reinterpret_cast<const float4*>(qp + j);
            s += v.x * v.x + v.y * v.y + v.z * v.z + v.w * v.w;
        }
        s_part[t] = s;
    }
    __syncthreads();
    if (t < QL) {
        float s = 0.f;
        #pragma unroll
        for (int p = 0; p < 16; ++p) s += s_part[t * 16 + p];
        s_qn[t] = sqrtf(s);
    }
    __syncthreads();

    int cnt[NBINS];
    #pragma unroll
    for (int k = 0; k < NBINS; ++k) cnt[k] = 0;

    if (t < DD) {
        const float* __restrict__ dp = base + (size_t)(QL + t) * HH;
        float acc[QL];
        #pragma unroll
        for (int q = 0; q < QL; ++q) acc[q] = 0.f;
        float dn2 = 0.f;

        for (int h = 0; h < HH; h += 16) {
            float4 d0 = *reinterpret_cast<const float4*>(dp + h + 0);
            float4 d1 = *reinterpret_cast<const float4*>(dp + h + 4);
            float4 d2 = *reinterpret_cast<const float4*>(dp + h + 8);
            float4 d3 = *reinterpret_cast<const float4*>(dp + h + 12);
            dn2 += d0.x*d0.x + d0.y*d0.y + d0.z*d0.z + d0.w*d0.w
                 + d1.x*d1.x + d1.y*d1.y + d1.z*d1.z + d1.w*d1.w
                 + d2.x*d2.x + d2.y*d2.y + d2.z*d2.z + d2.w*d2.w
                 + d3.x*d3.x + d3.y*d3.y + d3.z*d3.z + d3.w*d3.w;
            #pragma unroll
            for (int q = 0; q < QL; ++q) {
                // wave-uniform address -> scalar/broadcast loads, L1-resident
                const float* qp = base + q * HH + h;
                float4 q0 = *reinterpret_cast<const float4*>(qp + 0);
                float4 q1 = *reinterpret_cast<const float4*>(qp + 4);
                float4 q2 = *reinterpret_cast<const float4*>(qp + 8);
                float4 q3 = *reinterpret_cast<const float4*>(qp + 12);
                acc[q] += q0.x*d0.x + q0.y*d0.y + q0.z*d0.z + q0.w*d0.w
                        + q1.x*d1.x + q1.y*d1.y + q1.z*d1.z + q1.w*d1.w
                        + q2.x*d2.x + q2.y*d2.y + q2.z*d2.z + q2.w*d2.w
                        + q3.x*d3.x + q3.y*d3.y + q3.z*d3.z + q3.w*d3.w;
            }
        }
        const float dn = sqrtf(dn2);
        #pragma unroll
        for (int q = 0; q < QL; ++q) {
            float denom = fmaxf(s_qn[q] * dn, 1e-8f);
            float sim = acc[q] / denom;
            int bin = (int)floorf((sim + 1.0f) * 5.5f);   // bins [-1,1) width 2/11
            #pragma unroll
            for (int k = 0; k < NBINS; ++k) cnt[k] += (bin == k) ? 1 : 0;
        }
    }

    // ---- block histogram reduction: wave shuffle, then LDS atomics ----
    #pragma unroll
    for (int k = 0; k < NBINS; ++k) {
        int v = cnt[k];
        for (int off = 32; off > 0; off >>= 1) v += __shfl_down(v, off, 64);
        if ((t & 63) == 0 && v != 0) atomicAdd(&s_hist[k], v);
    }
    __syncthreads();
    if (t < NBINS) {
        counts[((size_t)l * NBATCH + b) * NBINS + t] = (float)s_hist[t];
    }
}

// One block per batch element: cls dot + histogram feature fold + biases.
__global__ __launch_bounds__(256)
void finalize_kernel(const float* __restrict__ hs,
                     const float* __restrict__ Wh,   // (5,11)
                     const float* __restrict__ bh,   // (5,)
                     const float* __restrict__ Wc,   // (1,838)
                     const float* __restrict__ bc,   // (1,)
                     const float* __restrict__ counts,
                     float* __restrict__ out) {
    const int b = blockIdx.x;
    const int t = threadIdx.x;
    float p = 0.f;

    // cls = hidden_states[12][b][0][:]
    const float* cls = hs + ((size_t)(12 * NBATCH + b)) * SS * HH;
    for (int j = t; j < HH; j += 256) p += cls[j] * Wc[j];

    // histogram features: 14 layers x 11 bins = 154 (l,n) pairs
    if (t < 14 * NBINS) {
        const int l  = t / NBINS;          // 0..13 (all_layers index)
        const int n  = t % NBINS;
        const int lp = (l == 0) ? 0 : l - 1;  // unique-layer index
        float hist = counts[((size_t)lp * NBATCH + b) * NBINS + n] * (1.0f / (float)(QL * DD));
        float coef = 0.f;
        #pragma unroll
        for (int o = 0; o < 5; ++o) coef += Wc[HH + l * 5 + o] * Wh[o * NBINS + n];
        p += hist * coef;
    }

    if (t == 0) {
        float s = bc[0];
        for (int l = 0; l < 14; ++l)
            for (int o = 0; o < 5; ++o) s += Wc[HH + l * 5 + o] * bh[o];
        p += s;
    }

    __shared__ float red[256];
    red[t] = p;
    __syncthreads();
    for (int off = 128; off > 0; off >>= 1) {
        if (t < off) red[t] += red[t + off];
        __syncthreads();
    }
    if (t == 0) out[b] = red[0];
}

extern "C" void kernel_launch(void* const* d_in, const int* in_sizes, int n_in,
                              void* d_out, int out_size, void* d_ws, size_t ws_size,
                              hipStream_t stream) {
    const float* hs = (const float*)d_in[0];
    const float* Wh = (const float*)d_in[1];
    const float* bh = (const float*)d_in[2];
    const float* Wc = (const float*)d_in[3];
    const float* bc = (const float*)d_in[4];
    float* counts = (float*)d_ws;          // 13*16*11 floats, each written once
    float* out    = (float*)d_out;         // (16,1) fp32

    dim3 grid(NLAYER, NBATCH);
    sim_hist_kernel<<<grid, 512, 0, stream>>>(hs, counts);
    finalize_kernel<<<NBATCH, 256, 0, stream>>>(hs, Wh, bh, Wc, bc, counts, out);
}